// Round 13
// baseline (165.081 us; speedup 1.0000x reference)
//
#include <hip/hip_runtime.h>

typedef __attribute__((ext_vector_type(8))) short bf16x8;
typedef __attribute__((ext_vector_type(4))) float f32x4;
typedef __attribute__((ext_vector_type(4))) unsigned short u16x4;
typedef __attribute__((ext_vector_type(8))) unsigned short u16x8;

#define B_ 2048
#define A_ 50
#define H_ 512
#define NACT_ 64
#define F_ 562
#define BM_ 64
#define BK_ 32
#define NSTEP_ 16

#define WS_W1T 0
#define WS_W2T ((size_t)A_ * H_ * H_ * 2)
#define WS_B1 (WS_W2T + (size_t)A_ * NACT_ * H_ * 2)
#define WS_B2 (WS_B1 + (size_t)A_ * H_ * 4)

static __device__ __forceinline__ unsigned short f2bf(float f) {
  unsigned int u = __builtin_bit_cast(unsigned int, f);
  u += 0x7fffu + ((u >> 16) & 1u);
  return (unsigned short)(u >> 16);
}

static __device__ __forceinline__ int clamp_r(int r) {
  return r < 0 ? 0 : (r > A_ - 1 ? A_ - 1 : r);
}

// W1T PLAIN layout (no XOR — A-fragments go global->VGPR, LDS not involved):
// [a][slab s=k>>5 (16)][j 512][kc 4][e 8]; slab = contiguous 32 KiB;
// row (64B) holds k = s*32 + kc*8 + e. Fully coalesced stores.
__global__ void prep_w1(const float* __restrict__ w1,
                        const int* __restrict__ routing,
                        unsigned short* __restrict__ w1t) {
  const int bid = blockIdx.x;
  const int a = bid / 64;
  const int tile = bid - a * 64;
  const int tk = tile & 7, tj = tile >> 3;
  const int k0 = tk * 64, j0 = tj * 64;
  const int r = clamp_r(routing[a]);
  __shared__ float tl[64][65];
  const int t = threadIdx.x;
  const int c = t & 63, q = t >> 6;
#pragma unroll
  for (int i = 0; i < 16; ++i) {
    const int kl = q + i * 4;
    tl[kl][c] = w1[((size_t)r * F_ + k0 + kl) * H_ + j0 + c];
  }
  __syncthreads();
  const int jl = t >> 2, c2 = t & 3;
#pragma unroll
  for (int it = 0; it < 2; ++it) {
    const int kc = it * 4 + c2; // plain: position == logical chunk
    u16x8 v;
#pragma unroll
    for (int e = 0; e < 8; ++e) v[e] = f2bf(tl[kc * 8 + e][jl]);
    unsigned short* dst = w1t +
        (((size_t)a * 16 + tk * 2 + it) * H_ + j0 + jl) * 32 + c2 * 8;
    *(u16x8*)dst = v;
  }
}

__global__ void prep_w2(const float* __restrict__ w2,
                        const int* __restrict__ routing,
                        unsigned short* __restrict__ w2t) {
  const int bid = blockIdx.x;
  const int a = bid >> 3;
  const int tk = bid & 7;
  const int k0 = tk * 64;
  const int r = clamp_r(routing[a]);
  __shared__ float tl[64][65];
  const int t = threadIdx.x;
  const int c = t & 63, q = t >> 6;
#pragma unroll
  for (int i = 0; i < 16; ++i) {
    const int kl = q + i * 4;
    tl[kl][c] = w2[((size_t)r * H_ + k0 + kl) * NACT_ + c];
  }
  __syncthreads();
#pragma unroll
  for (int i = 0; i < 16; ++i) {
    const int nl = q + i * 4;
    w2t[((size_t)a * NACT_ + nl) * H_ + k0 + c] = f2bf(tl[c][nl]);
  }
}

__global__ void prep_bias(const float* __restrict__ w1,
                          const float* __restrict__ b1,
                          const float* __restrict__ b2,
                          const int* __restrict__ routing,
                          float* __restrict__ bias1, float* __restrict__ bias2) {
  const int a = blockIdx.x;
  const int t = threadIdx.x;
  const int r = clamp_r(routing[a]);
  bias1[a * H_ + t] = b1[(size_t)r * H_ + t] + w1[((size_t)r * F_ + H_ + a) * H_ + t];
  if (t < NACT_) bias2[a * NACT_ + t] = b2[r * NACT_ + t];
}

// v13: barrier-free K-loop. x staged ONCE into stationary swizzled LDS tile
// (R7's proven scheme); W1 A-fragments stream global->VGPR double-buffered
// (compiler-managed waitcnt on register deps). No LDS writes, no barriers,
// no gld_lds in the loop. 512 thr / 8 waves; 64 KiB LDS -> 2 blocks/CU.
__global__ __launch_bounds__(512) void divtree_v13(
    const float* __restrict__ x, const unsigned short* __restrict__ w1t,
    const unsigned short* __restrict__ w2t, const float* __restrict__ bias1,
    const float* __restrict__ bias2, float* __restrict__ out) {
  __shared__ union {
    unsigned short xs[BM_ * H_]; // 64 KiB stationary x (swizzled)
    unsigned short h[BM_ * H_];  // reused after K-loop (post-barrier)
    float outb[BM_][66];         // reused after layer 2
  } sm;

  // XCD-bijective swizzle: 1600 blocks, cpx = 200
  const int bid = blockIdx.x;
  const int swz = (bid & 7) * 200 + (bid >> 3);
  const int a = swz >> 5;
  const int mblk = swz & 31;
  const int b0 = mblk * BM_;

  const int tid = threadIdx.x;
  const int lane = tid & 63;
  const int w = tid >> 6; // wave 0..7
  const int l16 = lane & 15;
  const int lk = lane >> 4;
  const int l7 = l16 & 7;
  const int wj = w * 64; // 8 waves cover j = 512; each wave owns all m = 64

  const unsigned short* w1ta = w1t + (size_t)a * (H_ * H_);

  // ---- prologue: stationary x tile (full contiguous rows; R7 scheme) ----
  {
    const int xm = tid >> 3;
    const int xq = tid & 7;
    const float* xrowp =
        x + ((size_t)(b0 + xm) * A_ + (size_t)a) * H_ + (size_t)xq * 64;
    f32x4 xv[16];
#pragma unroll
    for (int i = 0; i < 16; ++i) xv[i] = *(const f32x4*)(xrowp + i * 4);
#pragma unroll
    for (int j = 0; j < 8; ++j) {
      u16x8 v;
#pragma unroll
      for (int e = 0; e < 4; ++e) {
        v[e] = f2bf(xv[2 * j][e]);
        v[4 + e] = f2bf(xv[2 * j + 1][e]);
      }
      const int c = xq * 8 + j; // 16B chunk index within the 1KB row
      *(u16x8*)(sm.xs + xm * H_ + (c ^ (xm & 7)) * 8) = v;
    }
  }
  __syncthreads(); // xs ready; no further barriers until epilogue

  // per-wave A-fragment global base: row (wj + jf*16 + l16), chunk lk
  const unsigned short* wfr =
      w1ta + (size_t)(wj + l16) * 32 + (size_t)(lk * 8);

  f32x4 acc[4][4];
#pragma unroll
  for (int i = 0; i < 4; ++i)
#pragma unroll
    for (int j = 0; j < 4; ++j) acc[i][j] = (f32x4){0.f, 0.f, 0.f, 0.f};

  bf16x8 wrA[4], wrB[4]; // A-fragment register double buffer

  // issue slab 0
#pragma unroll
  for (int jf = 0; jf < 4; ++jf)
    wrA[jf] = *(const bf16x8*)(wfr + jf * (16 * 32));

#pragma unroll
  for (int t = 0; t < NSTEP_; ++t) {
    // issue slab t+1 into the other reg buffer (compiler inserts the
    // minimal vmcnt before first USE of slab t's regs below)
    if (t + 1 < NSTEP_) {
      const unsigned short* p = wfr + (size_t)(t + 1) * (H_ * BK_);
      if (t & 1) {
#pragma unroll
        for (int jf = 0; jf < 4; ++jf)
          wrA[jf] = *(const bf16x8*)(p + jf * (16 * 32));
      } else {
#pragma unroll
        for (int jf = 0; jf < 4; ++jf)
          wrB[jf] = *(const bf16x8*)(p + jf * (16 * 32));
      }
    }
    // B fragments from stationary xs: pos = (t*4+lk) ^ (row&7), row = m
    const int post = ((t * 4 + lk) ^ l7) * 8;
    bf16x8 bfr[4];
#pragma unroll
    for (int mf = 0; mf < 4; ++mf)
      bfr[mf] = *(const bf16x8*)(sm.xs + (mf * 16 + l16) * H_ + post);
    __builtin_amdgcn_s_setprio(1);
#pragma unroll
    for (int jf = 0; jf < 4; ++jf) {
      const bf16x8 afr = (t & 1) ? wrB[jf] : wrA[jf];
#pragma unroll
      for (int mf = 0; mf < 4; ++mf)
        acc[jf][mf] = __builtin_amdgcn_mfma_f32_16x16x32_bf16(
            afr, bfr[mf], acc[jf][mf], 0, 0, 0);
    }
    __builtin_amdgcn_s_setprio(0);
  }
  __syncthreads(); // all xs reads done before h overwrites the region

  // ---- h = relu(acc + bias1_eff) -> LDS bf16, XOR-swizzled rows ----
  const float* b1p = bias1 + a * H_;
#pragma unroll
  for (int jf = 0; jf < 4; ++jf) {
    const f32x4 bv = *(const f32x4*)(b1p + wj + jf * 16 + lk * 4);
    const int cbase = (wj >> 3) + jf * 2 + (lk >> 1);
    const int half4 = (lk & 1) * 4;
#pragma unroll
    for (int mf = 0; mf < 4; ++mf) {
      u16x4 hv;
#pragma unroll
      for (int r = 0; r < 4; ++r) {
        float f = acc[jf][mf][r] + bv[r];
        f = f > 0.f ? f : 0.f;
        hv[r] = f2bf(f);
      }
      const int m = mf * 16 + l16;
      const int off = m * H_ + ((cbase ^ (l16 & 7))) * 8 + half4;
      *(u16x4*)(sm.h + off) = hv;
    }
  }
  __syncthreads();

  // ---- layer 2: wave tile 32(m) x 16(n); 8 waves = 2m x 4n ----
  const int m0 = (w & 1) * 32;
  const int n0 = (w >> 1) * 16;
  const unsigned short* w2p =
      w2t + ((size_t)a * NACT_ + n0 + l16) * H_ + lk * 8;
  f32x4 acc2[2];
  acc2[0] = (f32x4){0.f, 0.f, 0.f, 0.f};
  acc2[1] = (f32x4){0.f, 0.f, 0.f, 0.f};
#pragma unroll
  for (int kf = 0; kf < 16; ++kf) {
    const bf16x8 bf2 = *(const bf16x8*)(w2p + kf * 32);
#pragma unroll
    for (int mf = 0; mf < 2; ++mf) {
      const int row = m0 + mf * 16 + l16;
      const int off = row * H_ + (((kf * 4 + lk) ^ (l16 & 7))) * 8;
      const bf16x8 af2 = *(const bf16x8*)(sm.h + off);
      acc2[mf] = __builtin_amdgcn_mfma_f32_16x16x32_bf16(af2, bf2, acc2[mf],
                                                         0, 0, 0);
    }
  }
  const float b2v = bias2[a * NACT_ + n0 + l16];
  __syncthreads(); // h reads done before outb overwrite (aliased)
#pragma unroll
  for (int mf = 0; mf < 2; ++mf)
#pragma unroll
    for (int r = 0; r < 4; ++r)
      sm.outb[m0 + mf * 16 + lk * 4 + r][n0 + l16] = acc2[mf][r] + b2v;
  __syncthreads();

  // coalesced out store: 256B contiguous per row
  {
    const int row = tid >> 3;
    const int q8 = (tid & 7) * 8;
    const f32x4 v0 = *(const f32x4*)(&sm.outb[row][q8]);
    const f32x4 v1 = *(const f32x4*)(&sm.outb[row][q8 + 4]);
    float* op = out + ((size_t)(b0 + row) * A_ + a) * NACT_ + q8;
    *(f32x4*)op = v0;
    *(f32x4*)(op + 4) = v1;
  }
}

extern "C" void kernel_launch(void* const* d_in, const int* in_sizes, int n_in,
                              void* d_out, int out_size, void* d_ws,
                              size_t ws_size, hipStream_t stream) {
  const float* x = (const float*)d_in[0];
  const float* w1 = (const float*)d_in[1];
  const float* b1 = (const float*)d_in[2];
  const float* w2 = (const float*)d_in[3];
  const float* b2 = (const float*)d_in[4];
  const int* routing = (const int*)d_in[5];
  float* out = (float*)d_out;

  char* ws = (char*)d_ws;
  unsigned short* w1t = (unsigned short*)(ws + WS_W1T);
  unsigned short* w2t = (unsigned short*)(ws + WS_W2T);
  float* bias1 = (float*)(ws + WS_B1);
  float* bias2 = (float*)(ws + WS_B2);

  prep_w1<<<A_ * 64, 256, 0, stream>>>(w1, routing, w1t);
  prep_w2<<<A_ * 8, 256, 0, stream>>>(w2, routing, w2t);
  prep_bias<<<A_, 512, 0, stream>>>(w1, b1, b2, routing, bias1, bias2);
  divtree_v13<<<A_ * (B_ / BM_), 512, 0, stream>>>(x, w1t, w2t, bias1, bias2,
                                                   out);
}